// Round 1
// baseline (1023.003 us; speedup 1.0000x reference)
//
#include <hip/hip_runtime.h>
#include <hip/hip_bf16.h>

using short8 = __attribute__((ext_vector_type(8))) short;
using f32x4  = __attribute__((ext_vector_type(4))) float;

#define NN 2048
#define NC 8
static const size_t PLANE = (size_t)NN * NN;      // 4M elements per channel

// ---------------------------------------------------------------------------
// softmax over E=8 for 4 weight tensors [8c][8e] -> sw[4][8][8]
// ---------------------------------------------------------------------------
__global__ __launch_bounds__(256) void softmax_w_k(const float* __restrict__ w0, const float* __restrict__ w1,
                                                   const float* __restrict__ w2, const float* __restrict__ w3,
                                                   float* __restrict__ sw) {
  int t = threadIdx.x;
  const float* srcs[4] = {w0, w1, w2, w3};
  float v = srcs[t >> 6][t & 63];
  float m = v;
  #pragma unroll
  for (int d = 1; d < 8; d <<= 1) m = fmaxf(m, __shfl_xor(m, d, 8));
  float ex = __expf(v - m);
  float s = ex;
  #pragma unroll
  for (int d = 1; d < 8; d <<= 1) s += __shfl_xor(s, d, 8);
  sw[t] = ex / s;
}

// ---------------------------------------------------------------------------
// gtconv: from A [N,N,8] produce
//   a   [8][N][N] row-major   (sw tensor 0)
//   bT  [8][N][N] = b^T       (sw tensor 1)
//   c1T [8][N][N] = c1^T      (sw tensor 2)
// 32x32 (i,j) tile staged in LDS so both orientations write coalesced.
// ---------------------------------------------------------------------------
__global__ __launch_bounds__(256) void gtconv_abc(const float* __restrict__ A, const float* __restrict__ sw,
                                                  __hip_bfloat16* __restrict__ a, __hip_bfloat16* __restrict__ bT,
                                                  __hip_bfloat16* __restrict__ c1T) {
  __shared__ float Als[32][33][9];   // [ii][jj][e] padded for bank spread
  __shared__ float swl[4][8][8];
  int t = threadIdx.x;
  swl[t >> 6][(t & 63) >> 3][t & 7] = sw[t];
  int i0 = blockIdx.y * 32, j0 = blockIdx.x * 32;
  // load 32*32*8 floats as float4, fully coalesced
  #pragma unroll
  for (int q = 0; q < 8; q++) {
    int fi = t + q * 256;                 // float4 index; fi = ii*64 + jj*2 + e4
    int e4 = fi & 1, jj = (fi >> 1) & 31, ii = fi >> 6;
    const float4 v = *reinterpret_cast<const float4*>(A + (((size_t)(i0 + ii) * NN + (j0 + jj)) << 3) + e4 * 4);
    float* dst = &Als[ii][jj][e4 * 4];
    dst[0] = v.x; dst[1] = v.y; dst[2] = v.z; dst[3] = v.w;
  }
  __syncthreads();
  // row-major pass: a
  #pragma unroll
  for (int q = 0; q < 4; q++) {
    int pos = t + q * 256;
    int ii = pos >> 5, jj = pos & 31;
    float e[8];
    #pragma unroll
    for (int k = 0; k < 8; k++) e[k] = Als[ii][jj][k];
    size_t base = (size_t)(i0 + ii) * NN + (j0 + jj);
    #pragma unroll
    for (int c = 0; c < 8; c++) {
      float v = 0.f;
      #pragma unroll
      for (int k = 0; k < 8; k++) v += e[k] * swl[0][c][k];
      a[(size_t)c * PLANE + base] = __float2bfloat16(v);
    }
  }
  // transposed pass: bT, c1T  (output (r,s) = value at A(i=i0+s, j=j0+r))
  #pragma unroll
  for (int q = 0; q < 4; q++) {
    int pos = t + q * 256;
    int r = pos >> 5, s = pos & 31;
    float e[8];
    #pragma unroll
    for (int k = 0; k < 8; k++) e[k] = Als[s][r][k];
    size_t base = (size_t)(j0 + r) * NN + (i0 + s);
    #pragma unroll
    for (int c = 0; c < 8; c++) {
      float v1 = 0.f, v2 = 0.f;
      #pragma unroll
      for (int k = 0; k < 8; k++) { v1 += e[k] * swl[1][c][k]; v2 += e[k] * swl[2][c][k]; }
      bT [(size_t)c * PLANE + base] = __float2bfloat16(v1);
      c1T[(size_t)c * PLANE + base] = __float2bfloat16(v2);
    }
  }
}

// single-tensor transposed gtconv (for w_2 -> c2T), same staging
__global__ __launch_bounds__(256) void gtconv_one(const float* __restrict__ A, const float* __restrict__ sw,
                                                  __hip_bfloat16* __restrict__ oT) {
  __shared__ float Als[32][33][9];
  __shared__ float swl[8][8];
  int t = threadIdx.x;
  if (t < 64) swl[t >> 3][t & 7] = sw[t];
  int i0 = blockIdx.y * 32, j0 = blockIdx.x * 32;
  #pragma unroll
  for (int q = 0; q < 8; q++) {
    int fi = t + q * 256;
    int e4 = fi & 1, jj = (fi >> 1) & 31, ii = fi >> 6;
    const float4 v = *reinterpret_cast<const float4*>(A + (((size_t)(i0 + ii) * NN + (j0 + jj)) << 3) + e4 * 4);
    float* dst = &Als[ii][jj][e4 * 4];
    dst[0] = v.x; dst[1] = v.y; dst[2] = v.z; dst[3] = v.w;
  }
  __syncthreads();
  #pragma unroll
  for (int q = 0; q < 4; q++) {
    int pos = t + q * 256;
    int r = pos >> 5, s = pos & 31;
    float e[8];
    #pragma unroll
    for (int k = 0; k < 8; k++) e[k] = Als[s][r][k];
    size_t base = (size_t)(j0 + r) * NN + (i0 + s);
    #pragma unroll
    for (int c = 0; c < 8; c++) {
      float v1 = 0.f;
      #pragma unroll
      for (int k = 0; k < 8; k++) v1 += e[k] * swl[c][k];
      oT[(size_t)c * PLANE + base] = __float2bfloat16(v1);
    }
  }
}

// ---------------------------------------------------------------------------
// batched bf16 GEMM: C[c] (fp32, row-major MxN) = Arm[c] (MxK rm) * BT[c]^T
// BT stored as [N][K] row-major (i.e. B transposed). 128x128x64 tile, 4 waves.
// ---------------------------------------------------------------------------
#define BM 128
#define BN 128
#define BK 64
#define LDT 72   // padded K-stride in LDS (bf16 elems); 144B rows keep 16B align
__global__ __launch_bounds__(256) void gemm_bf16(const short* __restrict__ Arm, const short* __restrict__ BT,
                                                 float* __restrict__ C) {
  __shared__ short sA[BM * LDT];
  __shared__ short sB[BN * LDT];
  const int t = threadIdx.x;
  const int lane = t & 63, wave = t >> 6;
  const int wr = wave >> 1, wc = wave & 1;
  const size_t boff = (size_t)blockIdx.z * PLANE;
  const short* Ag = Arm + boff;
  const short* Bg = BT + boff;
  const int m0 = blockIdx.y * BM, n0 = blockIdx.x * BN;
  f32x4 acc[4][4] = {};
  const int lrow = t >> 3;            // 0..31
  const int lcol = (t & 7) * 8;       // 0..56
  const int fr = lane & 15, fk = (lane >> 4) * 8;

  for (int k0 = 0; k0 < NN; k0 += BK) {
    #pragma unroll
    for (int q = 0; q < 4; q++) {
      int row = lrow + q * 32;
      short8 va = *reinterpret_cast<const short8*>(Ag + (size_t)(m0 + row) * NN + k0 + lcol);
      short8 vb = *reinterpret_cast<const short8*>(Bg + (size_t)(n0 + row) * NN + k0 + lcol);
      *reinterpret_cast<short8*>(&sA[row * LDT + lcol]) = va;
      *reinterpret_cast<short8*>(&sB[row * LDT + lcol]) = vb;
    }
    __syncthreads();
    #pragma unroll
    for (int kk = 0; kk < BK; kk += 32) {
      short8 af[4], bf[4];
      #pragma unroll
      for (int m = 0; m < 4; m++) af[m] = *reinterpret_cast<const short8*>(&sA[(wr * 64 + m * 16 + fr) * LDT + kk + fk]);
      #pragma unroll
      for (int n = 0; n < 4; n++) bf[n] = *reinterpret_cast<const short8*>(&sB[(wc * 64 + n * 16 + fr) * LDT + kk + fk]);
      #pragma unroll
      for (int m = 0; m < 4; m++)
        #pragma unroll
        for (int n = 0; n < 4; n++)
          acc[m][n] = __builtin_amdgcn_mfma_f32_16x16x32_bf16(af[m], bf[n], acc[m][n], 0, 0, 0);
    }
    __syncthreads();
  }
  float* Cg = C + boff;
  const int orow = (lane >> 4) * 4, ocol = lane & 15;
  #pragma unroll
  for (int m = 0; m < 4; m++)
    #pragma unroll
    for (int n = 0; n < 4; n++) {
      int gr = m0 + wr * 64 + m * 16 + orow;
      int gc = n0 + wc * 64 + n * 16 + ocol;
      #pragma unroll
      for (int j = 0; j < 4; j++)
        Cg[(size_t)(gr + j) * NN + gc] = acc[m][n][j];
    }
}

// ---------------------------------------------------------------------------
// column sums excluding diagonal, two-level deterministic reduction
// ---------------------------------------------------------------------------
__global__ __launch_bounds__(256) void colsum_partial(const float* __restrict__ H, float* __restrict__ degp) {
  int c = blockIdx.z;
  int j = blockIdx.x * 256 + threadIdx.x;
  int i0 = blockIdx.y * 64;
  const float* base = H + (size_t)c * PLANE + (size_t)i0 * NN + j;
  float s = 0.f;
  #pragma unroll 4
  for (int i = 0; i < 64; i++) {
    float v = base[(size_t)i * NN];
    if (i0 + i != j) s += v;
  }
  degp[((size_t)c * 32 + blockIdx.y) * NN + j] = s;
}

__global__ __launch_bounds__(256) void reduce_inv(const float* __restrict__ degp, float* __restrict__ deginv) {
  int idx = blockIdx.x * 256 + threadIdx.x;   // 8*2048
  int c = idx >> 11, j = idx & (NN - 1);
  float s = 0.f;
  #pragma unroll 4
  for (int ic = 0; ic < 32; ic++) s += degp[((size_t)c * 32 + ic) * NN + j];
  deginv[idx] = (s == 0.f) ? 0.f : 1.f / s;
}

// ---------------------------------------------------------------------------
// Hn(bf16) = (i==j ? 0 : H * deginv[c][j]); 8 elems/thread
// ---------------------------------------------------------------------------
__global__ __launch_bounds__(256) void normalize_cast(const float* __restrict__ H, const float* __restrict__ deginv,
                                                      short* __restrict__ Hn) {
  size_t idx = (size_t)blockIdx.x * 256 + threadIdx.x;
  size_t e0 = idx * 8;
  int c = (int)(e0 >> 22);
  size_t rem = e0 & (PLANE - 1);
  int i = (int)(rem >> 11), j0 = (int)(rem & (NN - 1));
  const float4 h0 = *reinterpret_cast<const float4*>(H + e0);
  const float4 h1 = *reinterpret_cast<const float4*>(H + e0 + 4);
  const float4 d0 = *reinterpret_cast<const float4*>(deginv + c * NN + j0);
  const float4 d1 = *reinterpret_cast<const float4*>(deginv + c * NN + j0 + 4);
  float v[8] = {h0.x * d0.x, h0.y * d0.y, h0.z * d0.z, h0.w * d0.w,
                h1.x * d1.x, h1.y * d1.y, h1.z * d1.z, h1.w * d1.w};
  int dd = i - j0;
  if (dd >= 0 && dd < 8) v[dd] = 0.f;
  short8 o;
  #pragma unroll
  for (int k = 0; k < 8; k++) {
    __hip_bfloat16 hb = __float2bfloat16(v[k]);
    o[k] = *reinterpret_cast<short*>(&hb);
  }
  *reinterpret_cast<short8*>(Hn + e0) = o;
}

// ---------------------------------------------------------------------------
// out[i][j] = (1/16) * sum_c (H[c][i][j] + H[c][j][i]); 64x64 tiles
// ---------------------------------------------------------------------------
__global__ __launch_bounds__(256) void final_sym(const float* __restrict__ H, float* __restrict__ out) {
  __shared__ float tl[64][65];
  int t = threadIdx.x;
  int i0 = blockIdx.y * 64, j0 = blockIdx.x * 64;
  int r0 = t >> 6, cl = t & 63;
  float acc[16];
  #pragma unroll
  for (int q = 0; q < 16; q++) acc[q] = 0.f;
  for (int c = 0; c < 8; c++) {
    const float* Hc = H + ((size_t)c << 22);
    __syncthreads();
    #pragma unroll
    for (int q = 0; q < 16; q++) {
      int rr = r0 + q * 4;
      tl[rr][cl] = Hc[(size_t)(j0 + rr) * NN + i0 + cl];
    }
    __syncthreads();
    #pragma unroll
    for (int q = 0; q < 16; q++) {
      int rr = r0 + q * 4;
      acc[q] += Hc[(size_t)(i0 + rr) * NN + j0 + cl] + tl[cl][rr];
    }
  }
  #pragma unroll
  for (int q = 0; q < 16; q++) {
    int rr = r0 + q * 4;
    out[(size_t)(i0 + rr) * NN + j0 + cl] = acc[q] * (1.0f / 16.0f);
  }
}

// ---------------------------------------------------------------------------
extern "C" void kernel_launch(void* const* d_in, const int* in_sizes, int n_in,
                              void* d_out, int out_size, void* d_ws, size_t ws_size,
                              hipStream_t stream) {
  const float* A    = (const float*)d_in[0];
  const float* w1_0 = (const float*)d_in[1];
  const float* w2_0 = (const float*)d_in[2];
  const float* w_1  = (const float*)d_in[3];
  const float* w_2  = (const float*)d_in[4];
  float* out = (float*)d_out;

  char* w = (char*)d_ws;
  float* sw     = (float*)w;                                  // 256 f
  float* degp   = (float*)(w + (1 << 17));                    // 8*32*2048 f = 2MB
  float* deginv = (float*)(w + (1 << 17) + (1 << 21));        // 16K f
  const size_t BSZ = (size_t)NC * PLANE * sizeof(short);      // 64MB (bf16 plane stack)
  short* B0 = (short*)(w + (4u << 20));                       // a  / Hn
  short* B1 = (short*)((char*)B0 + BSZ);                      // bT / c2T
  short* B2 = (short*)((char*)B1 + BSZ);                      // c1T
  float* HH = (float*)((char*)B2 + BSZ);                      // fp32 H (128MB)

  dim3 blk(256);
  dim3 gconv(64, 64);
  dim3 ggemm(16, 16, 8);
  dim3 gcs(8, 32, 8);

  softmax_w_k<<<1, blk, 0, stream>>>(w1_0, w2_0, w_1, w_2, sw);
  gtconv_abc<<<gconv, blk, 0, stream>>>(A, sw, (__hip_bfloat16*)B0, (__hip_bfloat16*)B1, (__hip_bfloat16*)B2);
  gemm_bf16<<<ggemm, blk, 0, stream>>>(B0, B1, HH);           // H = a @ b

  colsum_partial<<<gcs, blk, 0, stream>>>(HH, degp);
  reduce_inv<<<64, blk, 0, stream>>>(degp, deginv);
  normalize_cast<<<16384, blk, 0, stream>>>(HH, deginv, B0);  // Hn -> B0
  gtconv_one<<<gconv, blk, 0, stream>>>(A, sw + 192, (__hip_bfloat16*)B1);  // c2T -> B1
  gemm_bf16<<<ggemm, blk, 0, stream>>>(B0, B2, HH);           // H2 = Hn @ c1

  colsum_partial<<<gcs, blk, 0, stream>>>(HH, degp);
  reduce_inv<<<64, blk, 0, stream>>>(degp, deginv);
  normalize_cast<<<16384, blk, 0, stream>>>(HH, deginv, B0);  // Hn2 -> B0
  gemm_bf16<<<ggemm, blk, 0, stream>>>(B0, B1, HH);           // H3 = Hn2 @ c2

  final_sym<<<dim3(32, 32), blk, 0, stream>>>(HH, out);
}